// Round 7
// baseline (219.442 us; speedup 1.0000x reference)
//
#include <hip/hip_runtime.h>
#include <hip/hip_bf16.h>
#include <stdint.h>

#define BB 4
#define NN 2048
#define DD 1024
#define HH 16
#define DHH 64
#define MM (BB*NN)   // 8192 rows

typedef unsigned short u16;
typedef unsigned int u32;
typedef __bf16 bf16x8_t __attribute__((ext_vector_type(8)));
typedef float f32x4_t __attribute__((ext_vector_type(4)));
typedef float f32x16_t __attribute__((ext_vector_type(16)));

__device__ inline u16 f2b(float f) {
    __hip_bfloat16 h = __float2bfloat16(f);
    return *(u16*)&h;
}

__device__ inline u32 pack2(float lo, float hi) {
    __hip_bfloat162 h2 = __float22bfloat162_rn(make_float2(lo, hi));
    return *(u32*)&h2;
}

__device__ inline void gload16(const void* g, void* l) {
    __builtin_amdgcn_global_load_lds(
        (const __attribute__((address_space(1))) void*)g,
        (__attribute__((address_space(3))) void*)l, 16, 0, 0);
}

// ---------------- convert f32 -> bf16 (vectorized) ----------------
__global__ void cvt_kernel(const float* __restrict__ in, u16* __restrict__ out) {
    int i = (blockIdx.x * 256 + threadIdx.x) * 4;
    float4 v = *(const float4*)(in + i);
    ushort4 o;
    o.x = f2b(v.x); o.y = f2b(v.y); o.z = f2b(v.z); o.w = f2b(v.w);
    *(ushort4*)(out + i) = o;
}

// ---------------- transpose + convert weights: Wt[n][k] = W[k][n] ----------------
__global__ void wtrans_kernel(const float* __restrict__ W0, const float* __restrict__ W1,
                              const float* __restrict__ W2, const float* __restrict__ W3,
                              u16* __restrict__ out_base) {
    int z = blockIdx.z;
    const float* W = (z == 0) ? W0 : (z == 1) ? W1 : (z == 2) ? W2 : W3;
    u16* o = out_base + (size_t)z * DD * DD;
    __shared__ float tile[64][65];
    int t = threadIdx.x;
    int r0 = t >> 6;
    int c = t & 63;
    int kb = blockIdx.x, nb = blockIdx.y;
#pragma unroll
    for (int i = 0; i < 16; ++i) {
        int r = i * 4 + r0;
        tile[r][c] = W[(size_t)(kb * 64 + r) * DD + nb * 64 + c];
    }
    __syncthreads();
#pragma unroll
    for (int i = 0; i < 16; ++i) {
        int r = i * 4 + r0;
        o[(size_t)(nb * 64 + r) * DD + kb * 64 + c] = f2b(tile[c][r]);
    }
}

// ---------------- transpose V: vbuf[8192][1024] -> VT[(b*16+h)*64+dh][2048] ----------------
__global__ void vtrans_kernel(const u16* __restrict__ in, u16* __restrict__ out) {
    __shared__ u16 tile[64][65];
    const int t = threadIdx.x;
    const int r0 = t >> 6;
    const int c = t & 63;
    const int nt = blockIdx.x;
    const int bh = blockIdx.y;
    const int b = bh >> 4, h = bh & 15;
    const u16* src = in + ((size_t)(b * 2048 + nt * 64)) * DD + h * 64;
#pragma unroll
    for (int i = 0; i < 16; ++i) {
        int r = i * 4 + r0;
        tile[r][c] = src[(size_t)r * DD + c];
    }
    __syncthreads();
    u16* dst = out + ((size_t)bh * 64) * NN + nt * 64;
#pragma unroll
    for (int i = 0; i < 16; ++i) {
        int r = i * 4 + r0;
        dst[(size_t)r * NN + c] = tile[c][r];
    }
}

// ---------------- GEMM: C[M,1024] = A[M,1024] @ Bt[1024,1024]^T + bias, *scale ----------------
template<int OUT_F32>
__global__ __launch_bounds__(256, 2)
void gemm_bt(const u16* __restrict__ A, const u16* __restrict__ Bt,
             const float* __restrict__ bias, void* __restrict__ Cout, float scale) {
    __shared__ u16 As[128 * 64];
    __shared__ u16 Bs[128 * 64];
    const int t = threadIdx.x;
    const int w = t >> 6, l = t & 63;
    const int wm = w >> 1, wn = w & 1;
    const int g = l >> 4, c = l & 15;
    const int bm = blockIdx.x, bn = blockIdx.y;

    const f32x4_t vzero = {0.f, 0.f, 0.f, 0.f};
    f32x4_t acc[4][4];
#pragma unroll
    for (int m = 0; m < 4; ++m)
#pragma unroll
        for (int n = 0; n < 4; ++n) acc[m][n] = vzero;

    const int srow = l >> 3;
    const int scol = ((l & 7) ^ srow) << 3;
    const int sa = (l & 7) << 4;

    for (int ks = 0; ks < 16; ++ks) {
#pragma unroll
        for (int i = 0; i < 4; ++i) {
            int chunk = w * 4 + i;
            int row = chunk * 8 + srow;
            const u16* ga = A + (size_t)(bm * 128 + row) * DD + ks * 64 + scol;
            gload16(ga, As + chunk * 512);
            const u16* gb = Bt + (size_t)(bn * 128 + row) * DD + ks * 64 + scol;
            gload16(gb, Bs + chunk * 512);
        }
        __syncthreads();

        bf16x8_t af[4][2], bfr[4][2];
#pragma unroll
        for (int m = 0; m < 4; ++m) {
            int rowa = wm * 64 + m * 16 + c;
#pragma unroll
            for (int kk = 0; kk < 2; ++kk)
                af[m][kk] = *(const bf16x8_t*)&As[rowa * 64 + (((kk * 64 + g * 16) ^ sa) >> 1)];
        }
#pragma unroll
        for (int n = 0; n < 4; ++n) {
            int rowb = wn * 64 + n * 16 + c;
#pragma unroll
            for (int kk = 0; kk < 2; ++kk)
                bfr[n][kk] = *(const bf16x8_t*)&Bs[rowb * 64 + (((kk * 64 + g * 16) ^ sa) >> 1)];
        }
#pragma unroll
        for (int kk = 0; kk < 2; ++kk)
#pragma unroll
            for (int m = 0; m < 4; ++m)
#pragma unroll
                for (int n = 0; n < 4; ++n)
                    acc[m][n] = __builtin_amdgcn_mfma_f32_16x16x32_bf16(
                        af[m][kk], bfr[n][kk], acc[m][n], 0, 0, 0);
        __syncthreads();
    }

#pragma unroll
    for (int n = 0; n < 4; ++n) {
        int col = bn * 128 + wn * 64 + n * 16 + c;
        float bv = bias[col];
#pragma unroll
        for (int m = 0; m < 4; ++m) {
            int row = bm * 128 + wm * 64 + m * 16 + g * 4;
#pragma unroll
            for (int j = 0; j < 4; ++j) {
                float v = (acc[m][n][j] + bv) * scale;
                if (OUT_F32)
                    ((float*)Cout)[(size_t)(row + j) * DD + col] = v;
                else
                    ((u16*)Cout)[(size_t)(row + j) * DD + col] = f2b(v);
            }
        }
    }
}

// ---------------- flash attention: quad-buffer paired-tile pipeline ----------------
// 4 waves/block, 64 q-rows/wave, swapped-operand 32x32 MFMA, fixed-max softmax.
// 4 KV slots; per step: STAGE two tiles (8 loads) -> vmcnt(8) -> barrier ->
// compute two tiles -> barrier. Loads fly across a full compute window.
// All ds_read addresses = 8 loop-invariant per-lane bases + compile-time imm.
__global__ __launch_bounds__(256, 2)
void attn32_kernel(const u16* __restrict__ qb, const u16* __restrict__ kb,
                   const u16* __restrict__ vt, u16* __restrict__ ctx) {
    __shared__ u16 KL[4][64 * 64];
    __shared__ u16 VL[4][64 * 64];
    const int t = threadIdx.x;
    const int w = t >> 6, l = t & 63;
    const int hl = l >> 5, l31 = l & 31, l7 = l & 7, l3 = l >> 3;

    // XCD-aware swizzle: 512 blocks -> 64 consecutive per XCD (8 bh groups/XCD)
    const int f = blockIdx.y * 8 + blockIdx.x;
    const int wg = (f & 7) * 64 + (f >> 3);
    const int qt = wg & 7, bh = wg >> 3;
    const int b = bh >> 4, h = bh & 15;
    const int hoff = h * DHH;
    const size_t kv0 = (size_t)b * NN;
    const size_t vt0 = (size_t)bh * DHH;

    // Q fragments: qf[qm][dks], lane holds Q[q = qm*32+l31][d = dks*16 + hl*8 + 0..7]
    const size_t qrow_base = (size_t)(b * NN + qt * 256 + w * 64);
    bf16x8_t qf[2][4];
#pragma unroll
    for (int qm = 0; qm < 2; ++qm)
#pragma unroll
        for (int dks = 0; dks < 4; ++dks)
            qf[qm][dks] = *(const bf16x8_t*)&qb[(qrow_base + qm * 32 + l31) * DD +
                                                hoff + dks * 16 + hl * 8];

    f32x16_t z16;
#pragma unroll
    for (int r = 0; r < 16; ++r) z16[r] = 0.f;

    f32x16_t accO[2][2];
#pragma unroll
    for (int qm = 0; qm < 2; ++qm)
#pragma unroll
        for (int dt = 0; dt < 2; ++dt) accO[qm][dt] = z16;
    float lacc[2] = {0.f, 0.f};

    // loop-invariant LDS read bases (slot/kt32/dt offsets are compile-time imms)
    const char* kAd[4];
    const char* vAd[4];
#pragma unroll
    for (int d = 0; d < 4; ++d) {
        kAd[d] = (const char*)KL + l31 * 128 + ((d * 32 + hl * 16) ^ (l7 << 4));
        vAd[d] = (const char*)VL + l31 * 128 + ((d * 32 + hl * 16) ^ (l7 << 4));
    }

    // staging pointers (loop-carried; pi row-permute on K). Wave w stages rows
    // 16w..16w+15 of each tile (2 K chunks + 2 V chunks = 4 loads per tile).
    const int scol2 = (l7 ^ l3) << 3;
    const u16* kp[2];
    const u16* vp[2];
#pragma unroll
    for (int i = 0; i < 2; ++i) {
        const int ch = w * 2 + i, r = ch * 8 + l3, rr = (r >> 2) & 3;
        const int pr = (rr == 1 || rr == 2) ? (r ^ 12) : r;
        kp[i] = kb + (kv0 + pr) * DD + hoff + scol2;
        vp[i] = vt + (vt0 + r) * NN + scol2;
    }

#define STAGE1(S_)                                                           \
    do {                                                                     \
        _Pragma("unroll")                                                    \
        for (int i_ = 0; i_ < 2; ++i_) {                                     \
            gload16(kp[i_], &KL[S_][(w * 2 + i_) * 512]);                    \
            gload16(vp[i_], &VL[S_][(w * 2 + i_) * 512]);                    \
        }                                                                    \
        _Pragma("unroll")                                                    \
        for (int i_ = 0; i_ < 2; ++i_) { kp[i_] += 64 * DD; vp[i_] += 64; }  \
    } while (0)

#define COMPUTE(S_)                                                          \
    do {                                                                     \
        bf16x8_t kf[2][4];                                                   \
        _Pragma("unroll")                                                    \
        for (int kt32 = 0; kt32 < 2; ++kt32)                                 \
            _Pragma("unroll")                                                \
            for (int dks = 0; dks < 4; ++dks)                                \
                kf[kt32][dks] = *(const bf16x8_t*)(kAd[dks] + (S_) * 8192 +  \
                                                   kt32 * 4096);             \
        f32x16_t accS[2][2];                                                 \
        __builtin_amdgcn_s_setprio(1);                                       \
        _Pragma("unroll")                                                    \
        for (int qm = 0; qm < 2; ++qm)                                       \
            _Pragma("unroll")                                                \
            for (int kt32 = 0; kt32 < 2; ++kt32) {                           \
                accS[qm][kt32] = __builtin_amdgcn_mfma_f32_32x32x16_bf16(    \
                    kf[kt32][0], qf[qm][0], z16, 0, 0, 0);                   \
                _Pragma("unroll")                                            \
                for (int dks = 1; dks < 4; ++dks)                            \
                    accS[qm][kt32] = __builtin_amdgcn_mfma_f32_32x32x16_bf16(\
                        kf[kt32][dks], qf[qm][dks], accS[qm][kt32], 0, 0, 0);\
            }                                                                \
        __builtin_amdgcn_s_setprio(0);                                       \
        _Pragma("unroll")                                                    \
        for (int qm = 0; qm < 2; ++qm) {                                     \
            _Pragma("unroll")                                                \
            for (int kt32 = 0; kt32 < 2; ++kt32)                             \
                _Pragma("unroll")                                            \
                for (int r = 0; r < 16; ++r)                                 \
                    accS[qm][kt32][r] =                                      \
                        __builtin_amdgcn_exp2f(accS[qm][kt32][r]);           \
            f32x16_t sv = accS[qm][0] + accS[qm][1];                         \
            float s8[8];                                                     \
            _Pragma("unroll")                                                \
            for (int r = 0; r < 8; ++r) s8[r] = sv[r] + sv[r + 8];           \
            _Pragma("unroll")                                                \
            for (int sl = 4; sl >= 1; sl >>= 1)                              \
                _Pragma("unroll")                                            \
                for (int r = 0; r < sl; ++r) s8[r] += s8[r + sl];            \
            lacc[qm] += s8[0];                                               \
        }                                                                    \
        bf16x8_t vf[4][2];                                                   \
        _Pragma("unroll")                                                    \
        for (int pm = 0; pm < 4; ++pm)                                       \
            _Pragma("unroll")                                                \
            for (int dt = 0; dt < 2; ++dt)                                   \
                vf[pm][dt] = *(const bf16x8_t*)(vAd[pm] + (S_) * 8192 +      \
                                                dt * 4096);                  \
        __builtin_amdgcn_s_setprio(1);                                       \
        _Pragma("unroll")                                                    \
        for (int qm = 0; qm < 2; ++qm)                                       \
            _Pragma("unroll")                                                \
            for (int pm = 0; pm < 4; ++pm) {                                 \
                const int kt32_ = pm >> 1, half_ = pm & 1;                   \
                union { u32 u[4]; bf16x8_t v; } pu;                          \
                _Pragma("unroll")                                            \
                for (int j2 = 0; j2 < 4; ++j2)                               \
                    pu.u[j2] = pack2(accS[qm][kt32_][half_ * 8 + 2 * j2],    \
                                     accS[qm][kt32_][half_ * 8 + 2 * j2 + 1]); \
                _Pragma("unroll")                                            \
                for (int dt = 0; dt < 2; ++dt)                               \
                    accO[qm][dt] = __builtin_amdgcn_mfma_f32_32x32x16_bf16(  \
                        vf[pm][dt], pu.v, accO[qm][dt], 0, 0, 0);            \
            }                                                                \
        __builtin_amdgcn_s_setprio(0);                                       \
    } while (0)

#define PAIRSTEP(CS_, OS_, LAST_)                                            \
    do {                                                                     \
        if (!(LAST_)) {                                                      \
            STAGE1(OS_);                                                     \
            STAGE1((OS_) + 1);                                               \
            asm volatile("s_waitcnt vmcnt(8)" ::: "memory");                 \
        } else {                                                             \
            asm volatile("s_waitcnt vmcnt(0)" ::: "memory");                 \
        }                                                                    \
        __builtin_amdgcn_s_barrier();                                        \
        asm volatile("" ::: "memory");                                       \
        COMPUTE(CS_);                                                        \
        COMPUTE((CS_) + 1);                                                  \
        asm volatile("" ::: "memory");                                       \
        __builtin_amdgcn_s_barrier();                                        \
        asm volatile("" ::: "memory");                                       \
    } while (0)

    // prologue: tiles 0,1 -> slots 0,1
    STAGE1(0);
    STAGE1(1);

#pragma unroll 1
    for (int pp = 0; pp < 8; ++pp) {
        PAIRSTEP(0, 2, 0);            // stage tiles 4pp+2,4pp+3; compute 4pp,4pp+1
        PAIRSTEP(2, 0, pp == 7);      // stage tiles 4pp+4,4pp+5; compute 4pp+2,4pp+3
    }
#undef STAGE1
#undef COMPUTE
#undef PAIRSTEP

    // epilogue: ctx[q][hoff+dh] = O^T[dh][q] / rowsum
#pragma unroll
    for (int qm = 0; qm < 2; ++qm) {
        float rsum = lacc[qm] + __shfl_xor(lacc[qm], 32);
        const float rl = 1.0f / rsum;
        const size_t qrow = qrow_base + qm * 32 + l31;
#pragma unroll
        for (int dt = 0; dt < 2; ++dt)
#pragma unroll
            for (int m = 0; m < 4; ++m) {
                ushort4 o;
                o.x = f2b(accO[qm][dt][4 * m + 0] * rl);
                o.y = f2b(accO[qm][dt][4 * m + 1] * rl);
                o.z = f2b(accO[qm][dt][4 * m + 2] * rl);
                o.w = f2b(accO[qm][dt][4 * m + 3] * rl);
                *(ushort4*)&ctx[qrow * DD + hoff + dt * 32 + m * 8 + hl * 4] = o;
            }
    }
}

extern "C" void kernel_launch(void* const* d_in, const int* in_sizes, int n_in,
                              void* d_out, int out_size, void* d_ws, size_t ws_size,
                              hipStream_t stream) {
    (void)in_sizes; (void)n_in; (void)out_size; (void)ws_size;
    const float* key   = (const float*)d_in[0];
    const float* value = (const float*)d_in[1];
    const float* query = (const float*)d_in[2];
    const float* Wk = (const float*)d_in[3];
    const float* bk = (const float*)d_in[4];
    const float* Wv = (const float*)d_in[5];
    const float* bv = (const float*)d_in[6];
    const float* Wq = (const float*)d_in[7];
    const float* bq = (const float*)d_in[8];
    const float* Wo = (const float*)d_in[9];
    const float* bo = (const float*)d_in[10];

    char* ws = (char*)d_ws;
    const size_t MB = 1024 * 1024;
    u16* qbuf = (u16*)(ws + 0 * MB);
    u16* kbuf = (u16*)(ws + 16 * MB);
    u16* vbuf = (u16*)(ws + 32 * MB);   // projected V; later reused as ctx
    u16* WtK  = (u16*)(ws + 48 * MB);
    u16* WtV  = (u16*)(ws + 50 * MB);
    u16* WtQ  = (u16*)(ws + 52 * MB);
    u16* WtO  = (u16*)(ws + 54 * MB);
    u16* xb   = (u16*)(ws + 56 * MB);   // cvt buffer; later reused as VT

    const int nelem = MM * DD;
    const int cvt_blocks = nelem / (256 * 4);

    wtrans_kernel<<<dim3(16, 16, 4), 256, 0, stream>>>(Wk, Wv, Wq, Wo, WtK);

    // V = value @ Wv + bv
    cvt_kernel<<<cvt_blocks, 256, 0, stream>>>(value, xb);
    gemm_bt<0><<<dim3(64, 8), 256, 0, stream>>>(xb, WtV, bv, vbuf, 1.0f);
    // K = key @ Wk + bk
    cvt_kernel<<<cvt_blocks, 256, 0, stream>>>(key, xb);
    gemm_bt<0><<<dim3(64, 8), 256, 0, stream>>>(xb, WtK, bk, kbuf, 1.0f);
    // Q = (query @ Wq + bq) / sqrt(DH) * log2(e)
    cvt_kernel<<<cvt_blocks, 256, 0, stream>>>(query, xb);
    gemm_bt<0><<<dim3(64, 8), 256, 0, stream>>>(xb, WtQ, bq, qbuf, 0.125f * 1.4426950408889634f);

    // VT[(b*16+h)*64+dh][n] = vbuf[b*2048+n][h*64+dh]
    u16* VT = xb;
    vtrans_kernel<<<dim3(32, 64), 256, 0, stream>>>(vbuf, VT);

    // attention -> ctx (overlays vbuf)
    u16* ctx = vbuf;
    attn32_kernel<<<dim3(8, 64), 256, 0, stream>>>(qbuf, kbuf, VT, ctx);

    // out = ctx @ Wo + bo  (f32 output)
    gemm_bt<1><<<dim3(64, 8), 256, 0, stream>>>(ctx, WtO, bo, d_out, 1.0f);
}

// Round 8
// 219.429 us; speedup vs baseline: 1.0001x; 1.0001x over previous
//
#include <hip/hip_runtime.h>
#include <hip/hip_bf16.h>
#include <stdint.h>

#define BB 4
#define NN 2048
#define DD 1024
#define HH 16
#define DHH 64
#define MM (BB*NN)   // 8192 rows

typedef unsigned short u16;
typedef unsigned int u32;
typedef __bf16 bf16x8_t __attribute__((ext_vector_type(8)));
typedef float f32x4_t __attribute__((ext_vector_type(4)));
typedef float f32x16_t __attribute__((ext_vector_type(16)));

__device__ inline u16 f2b(float f) {
    __hip_bfloat16 h = __float2bfloat16(f);
    return *(u16*)&h;
}

__device__ inline u32 pack2(float lo, float hi) {
    __hip_bfloat162 h2 = __float22bfloat162_rn(make_float2(lo, hi));
    return *(u32*)&h2;
}

__device__ inline void gload16(const void* g, void* l) {
    __builtin_amdgcn_global_load_lds(
        (const __attribute__((address_space(1))) void*)g,
        (__attribute__((address_space(3))) void*)l, 16, 0, 0);
}

// ---------------- transpose + convert weights: Wt[n][k] = W[k][n] ----------------
__global__ void wtrans_kernel(const float* __restrict__ W0, const float* __restrict__ W1,
                              const float* __restrict__ W2, const float* __restrict__ W3,
                              u16* __restrict__ out_base) {
    int z = blockIdx.z;
    const float* W = (z == 0) ? W0 : (z == 1) ? W1 : (z == 2) ? W2 : W3;
    u16* o = out_base + (size_t)z * DD * DD;
    __shared__ float tile[64][65];
    int t = threadIdx.x;
    int r0 = t >> 6;
    int c = t & 63;
    int kb = blockIdx.x, nb = blockIdx.y;
#pragma unroll
    for (int i = 0; i < 16; ++i) {
        int r = i * 4 + r0;
        tile[r][c] = W[(size_t)(kb * 64 + r) * DD + nb * 64 + c];
    }
    __syncthreads();
#pragma unroll
    for (int i = 0; i < 16; ++i) {
        int r = i * 4 + r0;
        o[(size_t)(nb * 64 + r) * DD + kb * 64 + c] = f2b(tile[c][r]);
    }
}

// ---------------- transpose V: vbuf[8192][1024] -> VT[(b*16+h)*64+dh][2048] ----------------
__global__ void vtrans_kernel(const u16* __restrict__ in, u16* __restrict__ out) {
    __shared__ u16 tile[64][65];
    const int t = threadIdx.x;
    const int r0 = t >> 6;
    const int c = t & 63;
    const int nt = blockIdx.x;
    const int bh = blockIdx.y;
    const int b = bh >> 4, h = bh & 15;
    const u16* src = in + ((size_t)(b * 2048 + nt * 64)) * DD + h * 64;
#pragma unroll
    for (int i = 0; i < 16; ++i) {
        int r = i * 4 + r0;
        tile[r][c] = src[(size_t)r * DD + c];
    }
    __syncthreads();
    u16* dst = out + ((size_t)bh * 64) * NN + nt * 64;
#pragma unroll
    for (int i = 0; i < 16; ++i) {
        int r = i * 4 + r0;
        dst[(size_t)r * NN + c] = tile[c][r];
    }
}

// ---------------- GEMM: C[M,1024] = A[M,1024] @ Bt[1024,1024]^T + bias, *scale ----------------
// IN_F32A: A is f32; reg-stage + cvt_pk + swizzled ds_write (fuses the cvt pass).
// Else A is bf16 via global_load_lds with pre-swizzled source.
// LDS layout both ways: stored[row][16B-block d] = src[row][block d ^ (row&7)].
template<int IN_F32A, int OUT_F32>
__global__ __launch_bounds__(256, 2)
void gemm_bt(const void* __restrict__ Ap, const u16* __restrict__ Bt,
             const float* __restrict__ bias, void* __restrict__ Cout, float scale) {
    __shared__ u16 As[128 * 64];
    __shared__ u16 Bs[128 * 64];
    const int t = threadIdx.x;
    const int w = t >> 6, l = t & 63;
    const int wm = w >> 1, wn = w & 1;
    const int g = l >> 4, c = l & 15;
    const int bm = blockIdx.x, bn = blockIdx.y;

    const f32x4_t vzero = {0.f, 0.f, 0.f, 0.f};
    f32x4_t acc[4][4];
#pragma unroll
    for (int m = 0; m < 4; ++m)
#pragma unroll
        for (int n = 0; n < 4; ++n) acc[m][n] = vzero;

    const int srow = l >> 3;
    const int scol = ((l & 7) ^ srow) << 3;
    const int sa = (l & 7) << 4;

    for (int ks = 0; ks < 16; ++ks) {
        // ---- B staging (always bf16 gload_lds)
#pragma unroll
        for (int i = 0; i < 4; ++i) {
            int chunk = w * 4 + i;
            int row = chunk * 8 + srow;
            const u16* gb = Bt + (size_t)(bn * 128 + row) * DD + ks * 64 + scol;
            gload16(gb, Bs + chunk * 512);
        }
        // ---- A staging
        if constexpr (IN_F32A) {
            const float* Af = (const float*)Ap;
#pragma unroll
            for (int i = 0; i < 4; ++i) {
                const int tau = t + 256 * i;
                const int row = tau >> 3, cg = tau & 7;
                const float* ga = Af + (size_t)(bm * 128 + row) * DD + ks * 64 + cg * 8;
                float4 a0 = *(const float4*)ga;
                float4 a1 = *(const float4*)(ga + 4);
                union { u32 u[4]; uint4 q; } pu;
                pu.u[0] = pack2(a0.x, a0.y);
                pu.u[1] = pack2(a0.z, a0.w);
                pu.u[2] = pack2(a1.x, a1.y);
                pu.u[3] = pack2(a1.z, a1.w);
                *(uint4*)&As[row * 64 + ((cg ^ (row & 7)) << 3)] = pu.q;
            }
        } else {
            const u16* Ab = (const u16*)Ap;
#pragma unroll
            for (int i = 0; i < 4; ++i) {
                int chunk = w * 4 + i;
                int row = chunk * 8 + srow;
                const u16* ga = Ab + (size_t)(bm * 128 + row) * DD + ks * 64 + scol;
                gload16(ga, As + chunk * 512);
            }
        }
        __syncthreads();

        bf16x8_t af[4][2], bfr[4][2];
#pragma unroll
        for (int m = 0; m < 4; ++m) {
            int rowa = wm * 64 + m * 16 + c;
#pragma unroll
            for (int kk = 0; kk < 2; ++kk)
                af[m][kk] = *(const bf16x8_t*)&As[rowa * 64 + (((kk * 64 + g * 16) ^ sa) >> 1)];
        }
#pragma unroll
        for (int n = 0; n < 4; ++n) {
            int rowb = wn * 64 + n * 16 + c;
#pragma unroll
            for (int kk = 0; kk < 2; ++kk)
                bfr[n][kk] = *(const bf16x8_t*)&Bs[rowb * 64 + (((kk * 64 + g * 16) ^ sa) >> 1)];
        }
#pragma unroll
        for (int kk = 0; kk < 2; ++kk)
#pragma unroll
            for (int m = 0; m < 4; ++m)
#pragma unroll
                for (int n = 0; n < 4; ++n)
                    acc[m][n] = __builtin_amdgcn_mfma_f32_16x16x32_bf16(
                        af[m][kk], bfr[n][kk], acc[m][n], 0, 0, 0);
        __syncthreads();
    }

#pragma unroll
    for (int n = 0; n < 4; ++n) {
        int col = bn * 128 + wn * 64 + n * 16 + c;
        float bv = bias[col];
#pragma unroll
        for (int m = 0; m < 4; ++m) {
            int row = bm * 128 + wm * 64 + m * 16 + g * 4;
#pragma unroll
            for (int j = 0; j < 4; ++j) {
                float v = (acc[m][n][j] + bv) * scale;
                if (OUT_F32)
                    ((float*)Cout)[(size_t)(row + j) * DD + col] = v;
                else
                    ((u16*)Cout)[(size_t)(row + j) * DD + col] = f2b(v);
            }
        }
    }
}

// ---------------- flash attention: 4 waves/block, 64 q-rows/wave, counted-vmcnt pipeline ----
// (Round-6 verified structure.) Swapped-operand 32x32 MFMA, fixed-max softmax.
// K pi-permuted staging -> P^T pack lane-local. Double-buffered K/V with counted
// s_waitcnt vmcnt(4): next tile's loads stay in flight across compute.
//   STAGE(cur^1); vmcnt(4); barrier1; compute(cur); barrier2
__global__ __launch_bounds__(256, 2)
void attn32_kernel(const u16* __restrict__ qb, const u16* __restrict__ kb,
                   const u16* __restrict__ vt, u16* __restrict__ ctx) {
    __shared__ u16 Kt[2][64 * 64];
    __shared__ u16 Vs[2][64 * 64];
    const int t = threadIdx.x;
    const int w = t >> 6, l = t & 63;
    const int hl = l >> 5, l31 = l & 31, l7 = l & 7, l3 = l >> 3;

    // XCD-aware swizzle: 512 blocks -> 64 consecutive per XCD (8 bh groups/XCD)
    const int f = blockIdx.y * 8 + blockIdx.x;
    const int wg = (f & 7) * 64 + (f >> 3);
    const int qt = wg & 7, bh = wg >> 3;
    const int b = bh >> 4, h = bh & 15;
    const int hoff = h * DHH;
    const size_t kv0 = (size_t)b * NN;
    const size_t vt0 = (size_t)bh * DHH;

    // Q fragments: qf[qm][dks], lane holds Q[q = qm*32+l31][d = dks*16 + hl*8 + 0..7]
    const size_t qrow_base = (size_t)(b * NN + qt * 256 + w * 64);
    bf16x8_t qf[2][4];
#pragma unroll
    for (int qm = 0; qm < 2; ++qm)
#pragma unroll
        for (int dks = 0; dks < 4; ++dks)
            qf[qm][dks] = *(const bf16x8_t*)&qb[(qrow_base + qm * 32 + l31) * DD +
                                                hoff + dks * 16 + hl * 8];

    f32x16_t z16;
#pragma unroll
    for (int r = 0; r < 16; ++r) z16[r] = 0.f;

    f32x16_t accO[2][2];
#pragma unroll
    for (int qm = 0; qm < 2; ++qm)
#pragma unroll
        for (int dt = 0; dt < 2; ++dt) accO[qm][dt] = z16;
    float lacc[2] = {0.f, 0.f};

    // staging pointers (loop-carried; pi row-permute on K)
    const int scol2 = (l7 ^ l3) << 3;
    const u16* kp[2];
    const u16* vp[2];
#pragma unroll
    for (int i = 0; i < 2; ++i) {
        const int ch = w * 2 + i, r = ch * 8 + l3, rr = (r >> 2) & 3;
        const int pr = (rr == 1 || rr == 2) ? (r ^ 12) : r;
        kp[i] = kb + (kv0 + pr) * DD + hoff + scol2;
        vp[i] = vt + (vt0 + r) * NN + scol2;
    }

#define STAGE(buf_)                                                          \
    do {                                                                     \
        _Pragma("unroll")                                                    \
        for (int i_ = 0; i_ < 2; ++i_) {                                     \
            gload16(kp[i_], &Kt[buf_][(w * 2 + i_) * 512]);                  \
            gload16(vp[i_], &Vs[buf_][(w * 2 + i_) * 512]);                  \
        }                                                                    \
        _Pragma("unroll")                                                    \
        for (int i_ = 0; i_ < 2; ++i_) { kp[i_] += 64 * DD; vp[i_] += 64; }  \
    } while (0)

    STAGE(0);

    for (int kt = 0; kt < NN / 64; ++kt) {
        const int cur = kt & 1;
        if (kt < NN / 64 - 1) {
            STAGE(cur ^ 1);
            asm volatile("s_waitcnt vmcnt(4)" ::: "memory");
        } else {
            asm volatile("s_waitcnt vmcnt(0)" ::: "memory");
        }
        __builtin_amdgcn_s_barrier();     // barrier1: all waves' cur-loads landed
        asm volatile("" ::: "memory");

        const char* Kc = (const char*)Kt[cur];
        const char* Vc = (const char*)Vs[cur];

        // K fragments once, reused for both qm
        bf16x8_t kf[2][4];
#pragma unroll
        for (int kt32 = 0; kt32 < 2; ++kt32)
#pragma unroll
            for (int dks = 0; dks < 4; ++dks)
                kf[kt32][dks] = *(const bf16x8_t*)(Kc + (kt32 * 32 + l31) * 128 +
                                                   ((dks * 32 + hl * 16) ^ (l7 << 4)));

        // S^T = K_pi x Q^T  (first MFMA takes z16 as C-in: no acc zero-init)
        f32x16_t accS[2][2];
        __builtin_amdgcn_s_setprio(1);
#pragma unroll
        for (int qm = 0; qm < 2; ++qm)
#pragma unroll
            for (int kt32 = 0; kt32 < 2; ++kt32) {
                accS[qm][kt32] = __builtin_amdgcn_mfma_f32_32x32x16_bf16(
                    kf[kt32][0], qf[qm][0], z16, 0, 0, 0);
#pragma unroll
                for (int dks = 1; dks < 4; ++dks)
                    accS[qm][kt32] = __builtin_amdgcn_mfma_f32_32x32x16_bf16(
                        kf[kt32][dks], qf[qm][dks], accS[qm][kt32], 0, 0, 0);
            }
        __builtin_amdgcn_s_setprio(0);

        // fixed-max softmax: p = exp2(S); per-qm partial sums
#pragma unroll
        for (int qm = 0; qm < 2; ++qm) {
#pragma unroll
            for (int kt32 = 0; kt32 < 2; ++kt32)
#pragma unroll
                for (int r = 0; r < 16; ++r)
                    accS[qm][kt32][r] = __builtin_amdgcn_exp2f(accS[qm][kt32][r]);
            f32x16_t sv = accS[qm][0] + accS[qm][1];
            float s8[8];
#pragma unroll
            for (int r = 0; r < 8; ++r) s8[r] = sv[r] + sv[r + 8];
#pragma unroll
            for (int sl = 4; sl >= 1; sl >>= 1)
#pragma unroll
                for (int r = 0; r < sl; ++r) s8[r] += s8[r + sl];
            lacc[qm] += s8[0];
        }

        // V fragments once, reused for both qm
        bf16x8_t vf[4][2];
#pragma unroll
        for (int pm = 0; pm < 4; ++pm)
#pragma unroll
            for (int dt = 0; dt < 2; ++dt)
                vf[pm][dt] = *(const bf16x8_t*)(Vc + (dt * 32 + l31) * 128 +
                                                ((pm * 32 + hl * 16) ^ (l7 << 4)));

        // P^T lane-local pack + O^T += V^T x P^T
        __builtin_amdgcn_s_setprio(1);
#pragma unroll
        for (int qm = 0; qm < 2; ++qm)
#pragma unroll
            for (int pm = 0; pm < 4; ++pm) {
                const int kt32 = pm >> 1, half = pm & 1;
                union { u32 u[4]; bf16x8_t v; } pu;
#pragma unroll
                for (int j2 = 0; j2 < 4; ++j2)
                    pu.u[j2] = pack2(accS[qm][kt32][half * 8 + 2 * j2],
                                     accS[qm][kt32][half * 8 + 2 * j2 + 1]);
#pragma unroll
                for (int dt = 0; dt < 2; ++dt)
                    accO[qm][dt] = __builtin_amdgcn_mfma_f32_32x32x16_bf16(
                        vf[pm][dt], pu.v, accO[qm][dt], 0, 0, 0);
            }
        __builtin_amdgcn_s_setprio(0);

        asm volatile("" ::: "memory");
        __builtin_amdgcn_s_barrier();     // barrier2: done reading cur
        asm volatile("" ::: "memory");
    }
#undef STAGE

    // epilogue: ctx[q][hoff+dh] = O^T[dh][q] / rowsum
#pragma unroll
    for (int qm = 0; qm < 2; ++qm) {
        float rsum = lacc[qm] + __shfl_xor(lacc[qm], 32);
        const float rl = 1.0f / rsum;
        const size_t qrow = qrow_base + qm * 32 + l31;
#pragma unroll
        for (int dt = 0; dt < 2; ++dt)
#pragma unroll
            for (int m = 0; m < 4; ++m) {
                ushort4 o;
                o.x = f2b(accO[qm][dt][4 * m + 0] * rl);
                o.y = f2b(accO[qm][dt][4 * m + 1] * rl);
                o.z = f2b(accO[qm][dt][4 * m + 2] * rl);
                o.w = f2b(accO[qm][dt][4 * m + 3] * rl);
                *(ushort4*)&ctx[qrow * DD + hoff + dt * 32 + m * 8 + hl * 4] = o;
            }
    }
}

extern "C" void kernel_launch(void* const* d_in, const int* in_sizes, int n_in,
                              void* d_out, int out_size, void* d_ws, size_t ws_size,
                              hipStream_t stream) {
    (void)in_sizes; (void)n_in; (void)out_size; (void)ws_size;
    const float* key   = (const float*)d_in[0];
    const float* value = (const float*)d_in[1];
    const float* query = (const float*)d_in[2];
    const float* Wk = (const float*)d_in[3];
    const float* bk = (const float*)d_in[4];
    const float* Wv = (const float*)d_in[5];
    const float* bv = (const float*)d_in[6];
    const float* Wq = (const float*)d_in[7];
    const float* bq = (const float*)d_in[8];
    const float* Wo = (const float*)d_in[9];
    const float* bo = (const float*)d_in[10];

    char* ws = (char*)d_ws;
    const size_t MB = 1024 * 1024;
    u16* qbuf = (u16*)(ws + 0 * MB);
    u16* kbuf = (u16*)(ws + 16 * MB);
    u16* vbuf = (u16*)(ws + 32 * MB);   // projected V; later reused as ctx
    u16* WtK  = (u16*)(ws + 48 * MB);
    u16* WtV  = (u16*)(ws + 50 * MB);
    u16* WtQ  = (u16*)(ws + 52 * MB);
    u16* WtO  = (u16*)(ws + 54 * MB);
    u16* VT   = (u16*)(ws + 56 * MB);

    wtrans_kernel<<<dim3(16, 16, 4), 256, 0, stream>>>(Wk, Wv, Wq, Wo, WtK);

    // projections: fused f32->bf16 A-staging (no separate cvt pass)
    gemm_bt<1, 0><<<dim3(64, 8), 256, 0, stream>>>(value, WtV, bv, vbuf, 1.0f);
    gemm_bt<1, 0><<<dim3(64, 8), 256, 0, stream>>>(key, WtK, bk, kbuf, 1.0f);
    gemm_bt<1, 0><<<dim3(64, 8), 256, 0, stream>>>(query, WtQ, bq, qbuf,
                                                   0.125f * 1.4426950408889634f);

    // VT[(b*16+h)*64+dh][n] = vbuf[b*2048+n][h*64+dh]
    vtrans_kernel<<<dim3(32, 64), 256, 0, stream>>>(vbuf, VT);

    // attention -> ctx (overlays vbuf)
    u16* ctx = vbuf;
    attn32_kernel<<<dim3(8, 64), 256, 0, stream>>>(qbuf, kbuf, VT, ctx);

    // out = ctx @ Wo + bo  (f32 output)
    gemm_bt<0, 1><<<dim3(64, 8), 256, 0, stream>>>(ctx, WtO, bo, d_out, 1.0f);
}

// Round 9
// 208.922 us; speedup vs baseline: 1.0504x; 1.0503x over previous
//
#include <hip/hip_runtime.h>
#include <hip/hip_bf16.h>
#include <stdint.h>

#define BB 4
#define NN 2048
#define DD 1024
#define HH 16
#define DHH 64
#define MM (BB*NN)   // 8192 rows

typedef unsigned short u16;
typedef unsigned int u32;
typedef __bf16 bf16x8_t __attribute__((ext_vector_type(8)));
typedef float f32x4_t __attribute__((ext_vector_type(4)));
typedef float f32x16_t __attribute__((ext_vector_type(16)));

__device__ inline u16 f2b(float f) {
    __hip_bfloat16 h = __float2bfloat16(f);
    return *(u16*)&h;
}

__device__ inline u32 pack2(float lo, float hi) {
    __hip_bfloat162 h2 = __float22bfloat162_rn(make_float2(lo, hi));
    return *(u32*)&h2;
}

__device__ inline void gload16(const void* g, void* l) {
    __builtin_amdgcn_global_load_lds(
        (const __attribute__((address_space(1))) void*)g,
        (__attribute__((address_space(3))) void*)l, 16, 0, 0);
}

// ---------------- convert f32 -> bf16 (vectorized) ----------------
__global__ void cvt_kernel(const float* __restrict__ in, u16* __restrict__ out) {
    int i = (blockIdx.x * 256 + threadIdx.x) * 4;
    float4 v = *(const float4*)(in + i);
    ushort4 o;
    o.x = f2b(v.x); o.y = f2b(v.y); o.z = f2b(v.z); o.w = f2b(v.w);
    *(ushort4*)(out + i) = o;
}

// ---------------- transpose + convert weights: Wt[n][k] = W[k][n] ----------------
__global__ void wtrans_kernel(const float* __restrict__ W0, const float* __restrict__ W1,
                              const float* __restrict__ W2, const float* __restrict__ W3,
                              u16* __restrict__ out_base) {
    int z = blockIdx.z;
    const float* W = (z == 0) ? W0 : (z == 1) ? W1 : (z == 2) ? W2 : W3;
    u16* o = out_base + (size_t)z * DD * DD;
    __shared__ float tile[64][65];
    int t = threadIdx.x;
    int r0 = t >> 6;
    int c = t & 63;
    int kb = blockIdx.x, nb = blockIdx.y;
#pragma unroll
    for (int i = 0; i < 16; ++i) {
        int r = i * 4 + r0;
        tile[r][c] = W[(size_t)(kb * 64 + r) * DD + nb * 64 + c];
    }
    __syncthreads();
#pragma unroll
    for (int i = 0; i < 16; ++i) {
        int r = i * 4 + r0;
        o[(size_t)(nb * 64 + r) * DD + kb * 64 + c] = f2b(tile[c][r]);
    }
}

// ---------------- transpose V: vbuf[8192][1024] -> VT[(b*16+h)*64+dh][2048] ----------------
__global__ void vtrans_kernel(const u16* __restrict__ in, u16* __restrict__ out) {
    __shared__ u16 tile[64][65];
    const int t = threadIdx.x;
    const int r0 = t >> 6;
    const int c = t & 63;
    const int nt = blockIdx.x;
    const int bh = blockIdx.y;
    const int b = bh >> 4, h = bh & 15;
    const u16* src = in + ((size_t)(b * 2048 + nt * 64)) * DD + h * 64;
#pragma unroll
    for (int i = 0; i < 16; ++i) {
        int r = i * 4 + r0;
        tile[r][c] = src[(size_t)r * DD + c];
    }
    __syncthreads();
    u16* dst = out + ((size_t)bh * 64) * NN + nt * 64;
#pragma unroll
    for (int i = 0; i < 16; ++i) {
        int r = i * 4 + r0;
        dst[(size_t)r * NN + c] = tile[c][r];
    }
}

// ---------------- GEMM: C[M,1024] = A[M,1024] @ Bt[1024,1024]^T + bias, *scale ----------------
template<int OUT_F32>
__global__ __launch_bounds__(256, 2)
void gemm_bt(const u16* __restrict__ A, const u16* __restrict__ Bt,
             const float* __restrict__ bias, void* __restrict__ Cout, float scale) {
    __shared__ u16 As[128 * 64];
    __shared__ u16 Bs[128 * 64];
    const int t = threadIdx.x;
    const int w = t >> 6, l = t & 63;
    const int wm = w >> 1, wn = w & 1;
    const int g = l >> 4, c = l & 15;
    const int bm = blockIdx.x, bn = blockIdx.y;

    const f32x4_t vzero = {0.f, 0.f, 0.f, 0.f};
    f32x4_t acc[4][4];
#pragma unroll
    for (int m = 0; m < 4; ++m)
#pragma unroll
        for (int n = 0; n < 4; ++n) acc[m][n] = vzero;

    const int srow = l >> 3;
    const int scol = ((l & 7) ^ srow) << 3;
    const int sa = (l & 7) << 4;

    for (int ks = 0; ks < 16; ++ks) {
#pragma unroll
        for (int i = 0; i < 4; ++i) {
            int chunk = w * 4 + i;
            int row = chunk * 8 + srow;
            const u16* ga = A + (size_t)(bm * 128 + row) * DD + ks * 64 + scol;
            gload16(ga, As + chunk * 512);
            const u16* gb = Bt + (size_t)(bn * 128 + row) * DD + ks * 64 + scol;
            gload16(gb, Bs + chunk * 512);
        }
        __syncthreads();

        bf16x8_t af[4][2], bfr[4][2];
#pragma unroll
        for (int m = 0; m < 4; ++m) {
            int rowa = wm * 64 + m * 16 + c;
#pragma unroll
            for (int kk = 0; kk < 2; ++kk)
                af[m][kk] = *(const bf16x8_t*)&As[rowa * 64 + (((kk * 64 + g * 16) ^ sa) >> 1)];
        }
#pragma unroll
        for (int n = 0; n < 4; ++n) {
            int rowb = wn * 64 + n * 16 + c;
#pragma unroll
            for (int kk = 0; kk < 2; ++kk)
                bfr[n][kk] = *(const bf16x8_t*)&Bs[rowb * 64 + (((kk * 64 + g * 16) ^ sa) >> 1)];
        }
#pragma unroll
        for (int kk = 0; kk < 2; ++kk)
#pragma unroll
            for (int m = 0; m < 4; ++m)
#pragma unroll
                for (int n = 0; n < 4; ++n)
                    acc[m][n] = __builtin_amdgcn_mfma_f32_16x16x32_bf16(
                        af[m][kk], bfr[n][kk], acc[m][n], 0, 0, 0);
        __syncthreads();
    }

#pragma unroll
    for (int n = 0; n < 4; ++n) {
        int col = bn * 128 + wn * 64 + n * 16 + c;
        float bv = bias[col];
#pragma unroll
        for (int m = 0; m < 4; ++m) {
            int row = bm * 128 + wm * 64 + m * 16 + g * 4;
#pragma unroll
            for (int j = 0; j < 4; ++j) {
                float v = (acc[m][n][j] + bv) * scale;
                if (OUT_F32)
                    ((float*)Cout)[(size_t)(row + j) * DD + col] = v;
                else
                    ((u16*)Cout)[(size_t)(row + j) * DD + col] = f2b(v);
            }
        }
    }
}

// ---------------- flash attention: quad-buffer depth-3 counted-vmcnt pipeline ----------------
// 4 waves/block, 64 q-rows/wave, swapped-operand 32x32 MFMA, fixed-max softmax.
// 4 KV slots; per iter: STAGE one tile 3 ahead (4 loads/wave) -> vmcnt(12)
// (3 tiles in flight; each load has ~3 compute windows to land) -> barrier ->
// COMPUTE(cur) -> barrier. Tail peels vmcnt 8/4/0.
// WAR: slot (kt+3)&3 == (kt-1)&3; tile kt-1's reads end before barrier2(kt-1),
// which precedes every wave's STAGE(kt+3).
__global__ __launch_bounds__(256, 2)
void attn32_kernel(const u16* __restrict__ qb, const u16* __restrict__ kb,
                   const u16* __restrict__ vt, u16* __restrict__ ctx) {
    __shared__ u16 Kt[4][64 * 64];
    __shared__ u16 Vs[4][64 * 64];
    const int t = threadIdx.x;
    const int w = t >> 6, l = t & 63;
    const int hl = l >> 5, l31 = l & 31, l7 = l & 7, l3 = l >> 3;

    // XCD-aware swizzle: 512 blocks -> 64 consecutive per XCD (8 bh groups/XCD)
    const int f = blockIdx.y * 8 + blockIdx.x;
    const int wg = (f & 7) * 64 + (f >> 3);
    const int qt = wg & 7, bh = wg >> 3;
    const int b = bh >> 4, h = bh & 15;
    const int hoff = h * DHH;
    const size_t kv0 = (size_t)b * NN;
    const size_t vt0 = (size_t)bh * DHH;

    // Q fragments: qf[qm][dks], lane holds Q[q = qm*32+l31][d = dks*16 + hl*8 + 0..7]
    const size_t qrow_base = (size_t)(b * NN + qt * 256 + w * 64);
    bf16x8_t qf[2][4];
#pragma unroll
    for (int qm = 0; qm < 2; ++qm)
#pragma unroll
        for (int dks = 0; dks < 4; ++dks)
            qf[qm][dks] = *(const bf16x8_t*)&qb[(qrow_base + qm * 32 + l31) * DD +
                                                hoff + dks * 16 + hl * 8];

    f32x16_t z16;
#pragma unroll
    for (int r = 0; r < 16; ++r) z16[r] = 0.f;

    f32x16_t accO[2][2];
#pragma unroll
    for (int qm = 0; qm < 2; ++qm)
#pragma unroll
        for (int dt = 0; dt < 2; ++dt) accO[qm][dt] = z16;
    f32x16_t lacc16[2];
    lacc16[0] = z16; lacc16[1] = z16;

    // staging pointers (loop-carried; pi row-permute on K)
    const int scol2 = (l7 ^ l3) << 3;
    const u16* kp[2];
    const u16* vp[2];
#pragma unroll
    for (int i = 0; i < 2; ++i) {
        const int ch = w * 2 + i, r = ch * 8 + l3, rr = (r >> 2) & 3;
        const int pr = (rr == 1 || rr == 2) ? (r ^ 12) : r;
        kp[i] = kb + (kv0 + pr) * DD + hoff + scol2;
        vp[i] = vt + (vt0 + r) * NN + scol2;
    }

#define STAGE(S_)                                                            \
    do {                                                                     \
        _Pragma("unroll")                                                    \
        for (int i_ = 0; i_ < 2; ++i_) {                                     \
            gload16(kp[i_], &Kt[S_][(w * 2 + i_) * 512]);                    \
            gload16(vp[i_], &Vs[S_][(w * 2 + i_) * 512]);                    \
        }                                                                    \
        _Pragma("unroll")                                                    \
        for (int i_ = 0; i_ < 2; ++i_) { kp[i_] += 64 * DD; vp[i_] += 64; }  \
    } while (0)

    // prologue: tiles 0,1,2 -> slots 0,1,2 (12 loads in flight per wave)
    STAGE(0);
    STAGE(1);
    STAGE(2);

#pragma unroll 1
    for (int kt = 0; kt < NN / 64; ++kt) {
        const int cur = kt & 3;
        if (kt < NN / 64 - 3) {
            STAGE((kt + 3) & 3);
            asm volatile("s_waitcnt vmcnt(12)" ::: "memory");
        } else if (kt == NN / 64 - 3) {
            asm volatile("s_waitcnt vmcnt(8)" ::: "memory");
        } else if (kt == NN / 64 - 2) {
            asm volatile("s_waitcnt vmcnt(4)" ::: "memory");
        } else {
            asm volatile("s_waitcnt vmcnt(0)" ::: "memory");
        }
        __builtin_amdgcn_s_barrier();     // barrier1: tile `cur` visible to all waves
        asm volatile("" ::: "memory");

        const char* Kc = (const char*)Kt[cur];
        const char* Vc = (const char*)Vs[cur];

        // K fragments once, reused for both qm
        bf16x8_t kf[2][4];
#pragma unroll
        for (int kt32 = 0; kt32 < 2; ++kt32)
#pragma unroll
            for (int dks = 0; dks < 4; ++dks)
                kf[kt32][dks] = *(const bf16x8_t*)(Kc + (kt32 * 32 + l31) * 128 +
                                                   ((dks * 32 + hl * 16) ^ (l7 << 4)));

        // S^T = K_pi x Q^T  (first MFMA takes z16 as C-in: no acc zero-init)
        f32x16_t accS[2][2];
        __builtin_amdgcn_s_setprio(1);
#pragma unroll
        for (int qm = 0; qm < 2; ++qm)
#pragma unroll
            for (int kt32 = 0; kt32 < 2; ++kt32) {
                accS[qm][kt32] = __builtin_amdgcn_mfma_f32_32x32x16_bf16(
                    kf[kt32][0], qf[qm][0], z16, 0, 0, 0);
#pragma unroll
                for (int dks = 1; dks < 4; ++dks)
                    accS[qm][kt32] = __builtin_amdgcn_mfma_f32_32x32x16_bf16(
                        kf[kt32][dks], qf[qm][dks], accS[qm][kt32], 0, 0, 0);
            }
        __builtin_amdgcn_s_setprio(0);

        // fixed-max softmax: p = exp2(S); vector row-sum accumulate (fold in epilogue)
#pragma unroll
        for (int qm = 0; qm < 2; ++qm) {
#pragma unroll
            for (int kt32 = 0; kt32 < 2; ++kt32)
#pragma unroll
                for (int r = 0; r < 16; ++r)
                    accS[qm][kt32][r] = __builtin_amdgcn_exp2f(accS[qm][kt32][r]);
            lacc16[qm] += accS[qm][0] + accS[qm][1];
        }

        // V fragments once, reused for both qm
        bf16x8_t vf[4][2];
#pragma unroll
        for (int pm = 0; pm < 4; ++pm)
#pragma unroll
            for (int dt = 0; dt < 2; ++dt)
                vf[pm][dt] = *(const bf16x8_t*)(Vc + (dt * 32 + l31) * 128 +
                                                ((pm * 32 + hl * 16) ^ (l7 << 4)));

        // P^T lane-local pack + O^T += V^T x P^T
        __builtin_amdgcn_s_setprio(1);
#pragma unroll
        for (int qm = 0; qm < 2; ++qm)
#pragma unroll
            for (int pm = 0; pm < 4; ++pm) {
                const int kt32 = pm >> 1, half = pm & 1;
                union { u32 u[4]; bf16x8_t v; } pu;
#pragma unroll
                for (int j2 = 0; j2 < 4; ++j2)
                    pu.u[j2] = pack2(accS[qm][kt32][half * 8 + 2 * j2],
                                     accS[qm][kt32][half * 8 + 2 * j2 + 1]);
#pragma unroll
                for (int dt = 0; dt < 2; ++dt)
                    accO[qm][dt] = __builtin_amdgcn_mfma_f32_32x32x16_bf16(
                        vf[pm][dt], pu.v, accO[qm][dt], 0, 0, 0);
            }
        __builtin_amdgcn_s_setprio(0);

        asm volatile("" ::: "memory");
        __builtin_amdgcn_s_barrier();     // barrier2: done reading slot `cur`
        asm volatile("" ::: "memory");
    }
#undef STAGE

    // epilogue: fold row-sum vector, ctx[q][hoff+dh] = O^T[dh][q] / rowsum
#pragma unroll
    for (int qm = 0; qm < 2; ++qm) {
        float s8[8];
#pragma unroll
        for (int r = 0; r < 8; ++r) s8[r] = lacc16[qm][r] + lacc16[qm][r + 8];
#pragma unroll
        for (int sl = 4; sl >= 1; sl >>= 1)
#pragma unroll
            for (int r = 0; r < sl; ++r) s8[r] += s8[r + sl];
        float rsum = s8[0] + __shfl_xor(s8[0], 32);
        const float rl = 1.0f / rsum;
        const size_t qrow = qrow_base + qm * 32 + l31;
#pragma unroll
        for (int dt = 0; dt < 2; ++dt)
#pragma unroll
            for (int m = 0; m < 4; ++m) {
                ushort4 o;
                o.x = f2b(accO[qm][dt][4 * m + 0] * rl);
                o.y = f2b(accO[qm][dt][4 * m + 1] * rl);
                o.z = f2b(accO[qm][dt][4 * m + 2] * rl);
                o.w = f2b(accO[qm][dt][4 * m + 3] * rl);
                *(ushort4*)&ctx[qrow * DD + hoff + dt * 32 + m * 8 + hl * 4] = o;
            }
    }
}

extern "C" void kernel_launch(void* const* d_in, const int* in_sizes, int n_in,
                              void* d_out, int out_size, void* d_ws, size_t ws_size,
                              hipStream_t stream) {
    (void)in_sizes; (void)n_in; (void)out_size; (void)ws_size;
    const float* key   = (const float*)d_in[0];
    const float* value = (const float*)d_in[1];
    const float* query = (const float*)d_in[2];
    const float* Wk = (const float*)d_in[3];
    const float* bk = (const float*)d_in[4];
    const float* Wv = (const float*)d_in[5];
    const float* bv = (const float*)d_in[6];
    const float* Wq = (const float*)d_in[7];
    const float* bq = (const float*)d_in[8];
    const float* Wo = (const float*)d_in[9];
    const float* bo = (const float*)d_in[10];

    char* ws = (char*)d_ws;
    const size_t MB = 1024 * 1024;
    u16* qbuf = (u16*)(ws + 0 * MB);
    u16* kbuf = (u16*)(ws + 16 * MB);
    u16* vbuf = (u16*)(ws + 32 * MB);   // projected V; later reused as ctx
    u16* WtK  = (u16*)(ws + 48 * MB);
    u16* WtV  = (u16*)(ws + 50 * MB);
    u16* WtQ  = (u16*)(ws + 52 * MB);
    u16* WtO  = (u16*)(ws + 54 * MB);
    u16* xb   = (u16*)(ws + 56 * MB);   // cvt buffer; later reused as VT

    const int nelem = MM * DD;
    const int cvt_blocks = nelem / (256 * 4);

    wtrans_kernel<<<dim3(16, 16, 4), 256, 0, stream>>>(Wk, Wv, Wq, Wo, WtK);

    // V = value @ Wv + bv
    cvt_kernel<<<cvt_blocks, 256, 0, stream>>>(value, xb);
    gemm_bt<0><<<dim3(64, 8), 256, 0, stream>>>(xb, WtV, bv, vbuf, 1.0f);
    // K = key @ Wk + bk
    cvt_kernel<<<cvt_blocks, 256, 0, stream>>>(key, xb);
    gemm_bt<0><<<dim3(64, 8), 256, 0, stream>>>(xb, WtK, bk, kbuf, 1.0f);
    // Q = (query @ Wq + bq) / sqrt(DH) * log2(e)
    cvt_kernel<<<cvt_blocks, 256, 0, stream>>>(query, xb);
    gemm_bt<0><<<dim3(64, 8), 256, 0, stream>>>(xb, WtQ, bq, qbuf, 0.125f * 1.4426950408889634f);

    // VT[(b*16+h)*64+dh][n] = vbuf[b*2048+n][h*64+dh]  (VT overlays xb; xb now dead)
    u16* VT = xb;
    vtrans_kernel<<<dim3(32, 64), 256, 0, stream>>>(vbuf, VT);

    // attention -> ctx (overlays vbuf)
    u16* ctx = vbuf;
    attn32_kernel<<<dim3(8, 64), 256, 0, stream>>>(qbuf, kbuf, VT, ctx);

    // out = ctx @ Wo + bo  (f32 output)
    gemm_bt<1><<<dim3(64, 8), 256, 0, stream>>>(ctx, WtO, bo, d_out, 1.0f);
}